// Round 3
// baseline (425.768 us; speedup 1.0000x reference)
//
#include <hip/hip_runtime.h>
#include <math.h>

// Problem constants (from reference setup_inputs)
#define BB 8
#define HH 16
#define LQ 128
#define LC 4096
#define DD 1024
#define ROWS (HH * LQ)            // 2048 rows to reduce per (b, lc)
#define R_SLABS 32
#define ROWS_PER_SLAB (ROWS / R_SLABS)  // 64
#define COL_TILES 4               // 1024 cols per tile (256 threads x float4)
#define K1_BLOCKS (BB * COL_TILES * R_SLABS)   // 1024
#define QV_BLOCKS ((BB * DD) / 256)            // 32
#define SLICES 4                  // top-k slices per batch in KB
#define KTOP 5
#define EPSF 1e-8f

// ---------------------------------------------------------------------------
// KA: fused attn partials + qv mean (unchanged from the 416.6 µs version,
// except it also zeroes the done[] counters for KB's last-block pattern).
//  blocks [0, 32): q_vec mean over Lq (first, so the latency-bound tail
//    overlaps the k1 stream).
//  blocks [32, 1056): partial column sums of cross_attn over (H,Lq).
//    Coalesced float4, deterministic, no atomics.
// ---------------------------------------------------------------------------
__global__ __launch_bounds__(256) void kA_partials_qv(
    const float* __restrict__ attn, const float* __restrict__ q,
    float* __restrict__ partials, float* __restrict__ qv,
    unsigned int* __restrict__ done, float* __restrict__ out) {
    if (blockIdx.x == 0) {
        if (threadIdx.x < BB) done[threadIdx.x] = 0u;
        if (threadIdx.x == BB) *out = 0.0f;
    }

    int blk = blockIdx.x;
    if (blk >= QV_BLOCKS) {
        int kblk = blk - QV_BLOCKS;
        int r = kblk % R_SLABS;
        int t = kblk / R_SLABS;
        int ct = t % COL_TILES;
        int b = t / COL_TILES;
        int col = ct * 1024 + threadIdx.x * 4;

        const float4* src = (const float4*)(attn + (size_t)b * ROWS * LC
                                                 + (size_t)r * ROWS_PER_SLAB * LC + col);
        float4 acc = make_float4(0.f, 0.f, 0.f, 0.f);
#pragma unroll 16
        for (int m = 0; m < ROWS_PER_SLAB; ++m) {
            float4 v = src[(size_t)m * (LC / 4)];
            acc.x += v.x; acc.y += v.y; acc.z += v.z; acc.w += v.w;
        }
        float4* dst = (float4*)(partials + (size_t)r * BB * LC + (size_t)b * LC + col);
        *dst = acc;
    } else {
        int g = blk * 256 + threadIdx.x;  // [0, B*D)
        int b = g / DD;
        int d = g % DD;
        const float* p = q + (size_t)b * LQ * DD + d;
        float s = 0.f;
#pragma unroll 8
        for (int row = 0; row < LQ; ++row)
            s += p[(size_t)row * DD];
        qv[g] = s * (1.0f / LQ);
    }
}

// ---------------------------------------------------------------------------
// KB: fused avg-reduce + top-5 + cosine. grid = B*SLICES = 32 blocks of 256.
//  Each block owns a 1024-col slice of one batch: reduces partials for its
//  slice (128 KB/block, 4x the CU-parallelism of round-0's failed fusion),
//  finds the slice-local top-5 (same (val,low-idx) comparator as the global
//  argmax -> merge of slice lists is bit-identical to the monolithic top-5),
//  publishes candidates, and the LAST block per batch (device-scope fence +
//  atomic counter) merges 20 candidates and runs the cosine phase
//  byte-identical to the previous K4.
// ---------------------------------------------------------------------------
__global__ __launch_bounds__(256) void kB_topk_cos(
    const float* __restrict__ partials, const float* __restrict__ qv,
    const float* __restrict__ ctx, float* __restrict__ cand_val,
    int* __restrict__ cand_idx, unsigned int* __restrict__ done,
    float* __restrict__ out) {
    __shared__ float swv[4];
    __shared__ int   swi[4];
    __shared__ int   s_win;
    __shared__ float s_cval[KTOP];
    __shared__ int   s_cidx[KTOP];
    __shared__ int   s_last;
    __shared__ int   s_top[KTOP];
    __shared__ float sred[4][11];

    int blk = blockIdx.x;
    int b  = blk >> 2;         // batch
    int qt = blk & 3;          // slice within batch
    int tid = threadIdx.x;
    int lane = tid & 63;
    int wave = tid >> 6;
    int colbase = qt * 1024 + tid * 4;   // global col of v[0]

    // ---- Phase A: reduce partials for this slice (order r=0..31, identical
    //      float4 adds to the old K2 -> bit-identical avg values) ----
    float v[4] = {0.f, 0.f, 0.f, 0.f};
    const float* pb = partials + (size_t)b * LC + colbase;
#pragma unroll
    for (int r = 0; r < R_SLABS; ++r) {
        float4 p = *(const float4*)(pb + (size_t)r * BB * LC);
        v[0] += p.x; v[1] += p.y; v[2] += p.z; v[3] += p.w;
    }

    // ---- Phase B: slice-local top-5 (5 rounds of block argmax) ----
    for (int kk = 0; kk < KTOP; ++kk) {
        float bv = v[0];
        int bj = 0;
#pragma unroll
        for (int j = 1; j < 4; ++j)
            if (v[j] > bv) { bv = v[j]; bj = j; }   // strict > prefers lower col
        int bc = colbase + bj;

        for (int off = 32; off > 0; off >>= 1) {
            float ov = __shfl_down(bv, off);
            int   oc = __shfl_down(bc, off);
            if (ov > bv || (ov == bv && oc < bc)) { bv = ov; bc = oc; }
        }
        if (lane == 0) { swv[wave] = bv; swi[wave] = bc; }
        __syncthreads();
        if (tid == 0) {
            float fv = swv[0]; int fc = swi[0];
#pragma unroll
            for (int w = 1; w < 4; ++w)
                if (swv[w] > fv || (swv[w] == fv && swi[w] < fc)) { fv = swv[w]; fc = swi[w]; }
            s_cval[kk] = fv;
            s_cidx[kk] = fc;
            s_win = fc;
        }
        __syncthreads();
        int lcol = s_win - qt * 1024;   // slice-local col of winner
        if ((lcol >> 2) == tid) v[lcol & 3] = -3.0e38f;  // mask (avg sums are >= 0)
        // no barrier needed: next round's swv write is ordered after tid0's
        // swv read by the sync above
    }

    // ---- publish candidates; last block per batch proceeds ----
    if (tid < KTOP) {
        cand_val[blk * KTOP + tid] = s_cval[tid];
        cand_idx[blk * KTOP + tid] = s_cidx[tid];
    }
    __syncthreads();
    if (tid == 0) {
        __threadfence();                       // release candidate writes
        unsigned int old = atomicAdd(&done[b], 1u);
        s_last = (old == SLICES - 1) ? 1 : 0;
    }
    __syncthreads();
    if (!s_last) return;

    // ---- merge 20 candidates -> global top-5 (same comparator) ----
    if (tid == 0) {
        __threadfence();                       // acquire other slices' writes
        float cv[SLICES * KTOP];
        int   ci[SLICES * KTOP];
        bool  used[SLICES * KTOP];
#pragma unroll
        for (int i = 0; i < SLICES * KTOP; ++i) {
            cv[i] = cand_val[(b * SLICES) * KTOP + i];
            ci[i] = cand_idx[(b * SLICES) * KTOP + i];
            used[i] = false;
        }
        for (int kk = 0; kk < KTOP; ++kk) {
            int best = -1;
            for (int i = 0; i < SLICES * KTOP; ++i) {
                if (used[i]) continue;
                if (best < 0 || cv[i] > cv[best] ||
                    (cv[i] == cv[best] && ci[i] < ci[best])) best = i;
            }
            used[best] = true;
            s_top[kk] = ci[best];
        }
    }
    __syncthreads();

    // ---- Phase C: cosine — byte-identical to the previous K4 ----
    const float4 q4 = *((const float4*)(qv + (size_t)b * DD + tid * 4));
    float acc[11];
    acc[10] = q4.x * q4.x + q4.y * q4.y + q4.z * q4.z + q4.w * q4.w;
#pragma unroll
    for (int kk = 0; kk < KTOP; ++kk) {
        const float4 c4 = *((const float4*)(ctx + (size_t)b * LC * DD
                                            + (size_t)s_top[kk] * DD + tid * 4));
        acc[kk]     = q4.x * c4.x + q4.y * c4.y + q4.z * c4.z + q4.w * c4.w;
        acc[5 + kk] = c4.x * c4.x + c4.y * c4.y + c4.z * c4.z + c4.w * c4.w;
    }
    for (int off = 32; off > 0; off >>= 1) {
#pragma unroll
        for (int i = 0; i < 11; ++i)
            acc[i] += __shfl_down(acc[i], off);
    }
    if (lane == 0) {
#pragma unroll
        for (int i = 0; i < 11; ++i) sred[wave][i] = acc[i];
    }
    __syncthreads();
    if (tid == 0) {
        float t[11];
#pragma unroll
        for (int i = 0; i < 11; ++i)
            t[i] = sred[0][i] + sred[1][i] + sred[2][i] + sred[3][i];
        float qn = fmaxf(sqrtf(t[10]), EPSF);
        float loss = 0.f;
#pragma unroll
        for (int kk = 0; kk < KTOP; ++kk) {
            float cn = fmaxf(sqrtf(t[5 + kk]), EPSF);
            loss += 1.0f - t[kk] / (qn * cn);
        }
        atomicAdd(out, loss * (1.0f / (BB * KTOP)));
    }
}

extern "C" void kernel_launch(void* const* d_in, const int* in_sizes, int n_in,
                              void* d_out, int out_size, void* d_ws, size_t ws_size,
                              hipStream_t stream) {
    const float* q    = (const float*)d_in[0];  // question_emb   [8,128,1024]
    const float* ctx  = (const float*)d_in[1];  // context_emb    [8,4096,1024]
    const float* attn = (const float*)d_in[2];  // cross_attn     [8,16,128,4096]
    float* out = (float*)d_out;

    // ws layout (floats):
    //   partials: R_SLABS*B*LC = 1,048,576  (4 MB)
    //   qv:       B*D          =     8,192  (32 KB)
    //   cand_val: 32*5         =       160
    //   cand_idx: 32*5         =       160  (as int)
    //   done:     8            =         8  (as uint)
    float* partials = (float*)d_ws;
    float* qv       = partials + (size_t)R_SLABS * BB * LC;
    float* cand_val = qv + (size_t)BB * DD;
    int*   cand_idx = (int*)(cand_val + SLICES * BB * KTOP);
    unsigned int* done = (unsigned int*)(cand_idx + SLICES * BB * KTOP);

    kA_partials_qv<<<QV_BLOCKS + K1_BLOCKS, 256, 0, stream>>>(attn, q, partials, qv, done, out);
    kB_topk_cos<<<BB * SLICES, 256, 0, stream>>>(partials, qv, ctx, cand_val, cand_idx, done, out);
}

// Round 4
// 418.010 us; speedup vs baseline: 1.0186x; 1.0186x over previous
//
#include <hip/hip_runtime.h>
#include <math.h>

// Problem constants (from reference setup_inputs)
#define BB 8
#define HH 16
#define LQ 128
#define LC 4096
#define DD 1024
#define ROWS (HH * LQ)            // 2048 rows to reduce per (b, lc)
#define R_SLABS 32
#define ROWS_PER_SLAB (ROWS / R_SLABS)  // 64
#define COL_TILES 4               // 1024 cols per tile (256 threads x float4)
#define K1_BLOCKS (BB * COL_TILES * R_SLABS)   // 1024
#define QV_BLOCKS ((BB * DD) / 256)            // 32
#define KTOP 5
#define EPSF 1e-8f

// ---------------------------------------------------------------------------
// BEST VERIFIED CONFIGURATION (416.6 µs, round 2). Round-3's last-block
// fusion of K2+K4 regressed to 425.8 µs (fence/atomic latency + lost overlap
// + narrower phase-A read), so this reverts to wide-and-separate stages.
//
// KA: fused attn partials + qv mean.
//  blocks [0, 32): q_vec mean over Lq (first, so the latency-bound tail
//    overlaps the k1 stream instead of trailing it).
//  blocks [32, 1056): partial column sums of cross_attn [B][H][Lq][Lc] over
//    (H,Lq) — coalesced float4, deterministic, no atomics, unroll 16.
//  Also zeroes *out (stream order puts this before K4's atomicAdd).
// ---------------------------------------------------------------------------
__global__ __launch_bounds__(256) void kA_partials_qv(
    const float* __restrict__ attn, const float* __restrict__ q,
    float* __restrict__ partials, float* __restrict__ qv,
    float* __restrict__ out) {
    if (blockIdx.x == 0 && threadIdx.x == 0) *out = 0.0f;

    int blk = blockIdx.x;
    if (blk >= QV_BLOCKS) {
        int kblk = blk - QV_BLOCKS;
        int r = kblk % R_SLABS;
        int t = kblk / R_SLABS;
        int ct = t % COL_TILES;
        int b = t / COL_TILES;
        int col = ct * 1024 + threadIdx.x * 4;

        const float4* src = (const float4*)(attn + (size_t)b * ROWS * LC
                                                 + (size_t)r * ROWS_PER_SLAB * LC + col);
        float4 acc = make_float4(0.f, 0.f, 0.f, 0.f);
#pragma unroll 16
        for (int m = 0; m < ROWS_PER_SLAB; ++m) {
            float4 v = src[(size_t)m * (LC / 4)];
            acc.x += v.x; acc.y += v.y; acc.z += v.z; acc.w += v.w;
        }
        float4* dst = (float4*)(partials + (size_t)r * BB * LC + (size_t)b * LC + col);
        *dst = acc;
    } else {
        int g = blk * 256 + threadIdx.x;  // [0, B*D)
        int b = g / DD;
        int d = g % DD;
        const float* p = q + (size_t)b * LQ * DD + d;
        float s = 0.f;
#pragma unroll 8
        for (int row = 0; row < LQ; ++row)
            s += p[(size_t)row * DD];
        qv[g] = s * (1.0f / LQ);
    }
}

// ---------------------------------------------------------------------------
// K2: wide column-sum of partials -> avg. 128 blocks (128 CUs; narrow
// variants — 8 blocks in round 0, 32 blocks in round 3 — both lost to per-CU
// latency limits). Column SUM — ranking-invariant vs the reference's mean.
// ---------------------------------------------------------------------------
__global__ __launch_bounds__(256) void k2_avg(
    const float* __restrict__ partials, float* __restrict__ avg) {
    int g = blockIdx.x * 256 + threadIdx.x;   // g in [0, B*LC)
    float s = 0.f;
#pragma unroll
    for (int r = 0; r < R_SLABS; ++r)
        s += partials[(size_t)r * BB * LC + g];
    avg[g] = s;
}

// ---------------------------------------------------------------------------
// K4: per-batch finalize. grid = B blocks of 256 threads.
//  - avg row in registers (16 vals/thread, col = j*256 + tid)
//  - top-5 via 5 rounds of wave-shuffle argmax (low-index tie-break,
//    matching jax.lax.top_k)
//  - 11 reductions (5 dots, 5 ctx norms, q norm) in ONE shuffle pass
//  - atomicAdd mean(1-sim)/(B*K) into *out (out zeroed by KA)
// ---------------------------------------------------------------------------
__global__ __launch_bounds__(256) void k4_finalize(
    const float* __restrict__ avg, const float* __restrict__ qv,
    const float* __restrict__ ctx, float* __restrict__ out) {
    __shared__ float swv[4];
    __shared__ int   swi[4];
    __shared__ int   s_win;
    __shared__ int   s_top[KTOP];
    __shared__ float sred[4][11];

    int b = blockIdx.x;
    int tid = threadIdx.x;
    int lane = tid & 63;
    int wave = tid >> 6;

    // avg row in registers; col = j*256 + tid
    float v[16];
#pragma unroll
    for (int j = 0; j < 16; ++j)
        v[j] = avg[(size_t)b * LC + j * 256 + tid];

    // ---- top-5: 5 rounds of block argmax via shuffles ----
    for (int kk = 0; kk < KTOP; ++kk) {
        float bv = v[0];
        int bj = 0;
#pragma unroll
        for (int j = 1; j < 16; ++j)
            if (v[j] > bv) { bv = v[j]; bj = j; }   // strict > prefers lower col
        int bc = bj * 256 + tid;

        for (int off = 32; off > 0; off >>= 1) {
            float ov = __shfl_down(bv, off);
            int   oc = __shfl_down(bc, off);
            if (ov > bv || (ov == bv && oc < bc)) { bv = ov; bc = oc; }
        }
        if (lane == 0) { swv[wave] = bv; swi[wave] = bc; }
        __syncthreads();
        if (tid == 0) {
            float fv = swv[0]; int fc = swi[0];
#pragma unroll
            for (int w = 1; w < 4; ++w)
                if (swv[w] > fv || (swv[w] == fv && swi[w] < fc)) { fv = swv[w]; fc = swi[w]; }
            s_top[kk] = fc;
            s_win = fc;
        }
        __syncthreads();
        int wc = s_win;
        if ((wc & 255) == tid) v[wc >> 8] = -3.0e38f;  // mask winner in owner's reg
        // no barrier needed: next round's swv write is already ordered after
        // tid0's swv read by the sync above
    }

    // ---- cosine: batch 11 reductions (5 dots, 5 c-norms, 1 q-norm) ----
    const float4 q4 = *((const float4*)(qv + (size_t)b * DD + tid * 4));
    float acc[11];
    acc[10] = q4.x * q4.x + q4.y * q4.y + q4.z * q4.z + q4.w * q4.w;
#pragma unroll
    for (int kk = 0; kk < KTOP; ++kk) {
        const float4 c4 = *((const float4*)(ctx + (size_t)b * LC * DD
                                            + (size_t)s_top[kk] * DD + tid * 4));
        acc[kk]        = q4.x * c4.x + q4.y * c4.y + q4.z * c4.z + q4.w * c4.w;
        acc[5 + kk]    = c4.x * c4.x + c4.y * c4.y + c4.z * c4.z + c4.w * c4.w;
    }
    for (int off = 32; off > 0; off >>= 1) {
#pragma unroll
        for (int i = 0; i < 11; ++i)
            acc[i] += __shfl_down(acc[i], off);
    }
    if (lane == 0) {
#pragma unroll
        for (int i = 0; i < 11; ++i) sred[wave][i] = acc[i];
    }
    __syncthreads();
    if (tid == 0) {
        float t[11];
#pragma unroll
        for (int i = 0; i < 11; ++i)
            t[i] = sred[0][i] + sred[1][i] + sred[2][i] + sred[3][i];
        float qn = fmaxf(sqrtf(t[10]), EPSF);
        float loss = 0.f;
#pragma unroll
        for (int kk = 0; kk < KTOP; ++kk) {
            float cn = fmaxf(sqrtf(t[5 + kk]), EPSF);
            loss += 1.0f - t[kk] / (qn * cn);
        }
        atomicAdd(out, loss * (1.0f / (BB * KTOP)));
    }
}

extern "C" void kernel_launch(void* const* d_in, const int* in_sizes, int n_in,
                              void* d_out, int out_size, void* d_ws, size_t ws_size,
                              hipStream_t stream) {
    const float* q    = (const float*)d_in[0];  // question_emb   [8,128,1024]
    const float* ctx  = (const float*)d_in[1];  // context_emb    [8,4096,1024]
    const float* attn = (const float*)d_in[2];  // cross_attn     [8,16,128,4096]
    float* out = (float*)d_out;

    // ws layout (floats):
    //   partials: R_SLABS*B*LC = 1,048,576  (4 MB)
    //   avg:      B*LC         =    32,768  (128 KB)
    //   qv:       B*D          =     8,192  (32 KB)
    float* partials = (float*)d_ws;
    float* avg = partials + (size_t)R_SLABS * BB * LC;
    float* qv  = avg + (size_t)BB * LC;

    kA_partials_qv<<<QV_BLOCKS + K1_BLOCKS, 256, 0, stream>>>(attn, q, partials, qv, out);
    k2_avg<<<(BB * LC) / 256, 256, 0, stream>>>(partials, avg);
    k4_finalize<<<BB, 256, 0, stream>>>(avg, qv, ctx, out);
}